// Round 15
// baseline (389.968 us; speedup 1.0000x reference)
//
#include <hip/hip_runtime.h>

#define BATCH 16
#define LSEQ 1024
#define DIN 512
#define DMODEL 1024
#define D3 3072
#define KCP 1064  // padded stride of each reversed-k copy (2128B: all 8 copies distinct 16B phase mod 128B)

typedef __attribute__((ext_vector_type(4))) float f32x4;
typedef __attribute__((ext_vector_type(8))) short bf16x8;

static __device__ __forceinline__ ushort f2bf(float f) {
    uint u = __float_as_uint(f);
    return (ushort)((u + 0x7FFFu + ((u >> 16) & 1u)) >> 16);
}
static __device__ __forceinline__ float bf2f(ushort h) {
    return __uint_as_float(((uint)h) << 16);
}

#define GLD16(ldst, gsrc)                                                        \
    __builtin_amdgcn_global_load_lds(                                            \
        (const __attribute__((address_space(1))) void*)(gsrc),                   \
        (__attribute__((address_space(3))) void*)(ldst), 16, 0, 0)

// ---------------------------------------------------------------------------
// bf16 MFMA GEMM: C[M,N] = A[M,K]bf16 * B (as Bt[N,K]bf16) + bias.
// PHASED schedule (T3+T4+T2+T5): BM=256 BN=128 BK=64, 512 thr (8 waves,
// 4M x 2N — fragment/epilogue math identical to the r13-proven kernel).
// Triple buffer (144KB LDS), 2 phases/K-tile:
//   phase = stage half-tile (GLD16) -> counted vmcnt(6) (never 0 mid-loop;
//   stage-to-consume distance = 2 K-tiles) -> barrier -> 8x ds_read_b128
//   -> setprio(1) -> 16 MFMA -> setprio(0) -> barrier.
// Both-sides XOR swizzle (rule #21): LDS dest stays lane-linear (GLD16
// requirement); the per-lane GLOBAL source address carries the permutation
// kchunk ^= (row&7); reads apply the same XOR. Turns the 8/16-way af/bg
// bank conflicts into 2-way (free, m136). K-order of accumulation unchanged
// -> bit-identical results. Requires M%256==0, N%128==0, K%64==0, K>=128.
// ---------------------------------------------------------------------------
template <typename OutT, bool HAS_BIAS>
__global__ __launch_bounds__(512, 2) void gemm_mfma(const ushort* __restrict__ A,
                                                    const ushort* __restrict__ Bt,
                                                    const float* __restrict__ bias,
                                                    OutT* __restrict__ C,
                                                    int M, int N, int K) {
    __shared__ __align__(16) ushort Als[3 * 256 * 64];   // 96 KB
    __shared__ __align__(16) ushort Bls[3 * 128 * 64];   // 48 KB
    int nwg = gridDim.x * gridDim.y;
    int bid = blockIdx.y * gridDim.x + blockIdx.x;
    bid = (bid & 7) * (nwg >> 3) + (bid >> 3);      // bijective: nwg % 8 == 0
    int n0 = (bid % gridDim.x) * 128, m0 = (bid / gridDim.x) * 256;
    int t = threadIdx.x;
    int w = t >> 6, l = t & 63;
    int wm = w >> 1, wn = w & 1;                    // 4M x 2N waves
    int lr = l & 15, lq = l >> 4;
    f32x4 acc[4][4] = {};
    int nK = K >> 6;

    const ushort* Aptr = A + (size_t)m0 * K;
    const ushort* Bptr = Bt + (size_t)n0 * K;

// Stage A half H (rows H*128..H*128+127) of K-tile KT into buffer BUF.
// chunk c = t + 512*j; dest = linear; src k-chunk pre-swizzled by row&7.
#define STAGE_A(BUF, H, KT)                                                     \
    {                                                                           \
        _Pragma("unroll")                                                       \
        for (int j = 0; j < 2; j++) {                                           \
            int c = t + 512 * j;                                                \
            GLD16(&Als[(BUF) * 16384 + (H) * 8192 + c * 8],                     \
                  Aptr + (size_t)((H) * 128 + (c >> 3)) * K + (KT) * 64 +       \
                      ((c & 7) ^ ((c >> 3) & 7)) * 8);                          \
        }                                                                       \
    }
#define STAGE_B(BUF, KT)                                                        \
    {                                                                           \
        _Pragma("unroll")                                                       \
        for (int j = 0; j < 2; j++) {                                           \
            int c = t + 512 * j;                                                \
            GLD16(&Bls[(BUF) * 8192 + c * 8],                                   \
                  Bptr + (size_t)(c >> 3) * K + (KT) * 64 +                     \
                      ((c & 7) ^ ((c >> 3) & 7)) * 8);                          \
        }                                                                       \
    }
// One phase's fragment reads (swizzled) + 16 MFMA for k-half KH of buffer CUR.
#define PHASE_MFMA(CUR, KH)                                                     \
    {                                                                           \
        bf16x8 af[4], bg[4];                                                    \
        _Pragma("unroll")                                                       \
        for (int i = 0; i < 4; i++)                                             \
            af[i] = *(const bf16x8*)&Als[(CUR) * 16384 +                        \
                (wm * 64 + 16 * i + lr) * 64 + ((lq + (KH) * 4) ^ (lr & 7)) * 8]; \
        _Pragma("unroll")                                                       \
        for (int j = 0; j < 4; j++)                                             \
            bg[j] = *(const bf16x8*)&Bls[(CUR) * 8192 +                         \
                (wn * 64 + 16 * j + lr) * 64 + ((lq + (KH) * 4) ^ (lr & 7)) * 8]; \
        __builtin_amdgcn_s_setprio(1);                                          \
        _Pragma("unroll")                                                       \
        for (int i = 0; i < 4; i++)                                             \
            _Pragma("unroll")                                                   \
            for (int j = 0; j < 4; j++)                                         \
                acc[i][j] = __builtin_amdgcn_mfma_f32_16x16x32_bf16(            \
                    af[i], bg[j], acc[i][j], 0, 0, 0);                          \
        __builtin_amdgcn_s_setprio(0);                                          \
    }

    // prologue: stage K-tiles 0 and 1 (6 loads each, order Ah0, B, Ah1)
    STAGE_A(0, 0, 0) STAGE_B(0, 0) STAGE_A(0, 1, 0)
    STAGE_A(1, 0, 1) STAGE_B(1, 1) STAGE_A(1, 1, 1)

    for (int T = 0; T < nK; T++) {
        int cur = T % 3;
        int stg = (T + 2) % 3;
        bool st = (T + 2) < nK;
        // ---- phase A (k-half 0) ----
        if (st) { STAGE_A(stg, 0, T + 2) STAGE_B(stg, T + 2) }
        if (T < nK - 1)
            asm volatile("s_waitcnt vmcnt(6)" ::: "memory");
        else
            asm volatile("s_waitcnt vmcnt(0)" ::: "memory");
        __builtin_amdgcn_s_barrier();
        __builtin_amdgcn_sched_barrier(0);
        PHASE_MFMA(cur, 0)
        __builtin_amdgcn_s_barrier();
        // ---- phase B (k-half 1): stage targets a buffer no wave reads now ----
        if (st) { STAGE_A(stg, 1, T + 2) }
        PHASE_MFMA(cur, 1)
        __builtin_amdgcn_s_barrier();
    }
#undef STAGE_A
#undef STAGE_B
#undef PHASE_MFMA

#pragma unroll
    for (int j = 0; j < 4; j++) {
        int col = n0 + wn * 64 + 16 * j + lr;
        float bv = HAS_BIAS ? bias[col] : 0.f;
#pragma unroll
        for (int i = 0; i < 4; i++) {
            int row0 = m0 + wm * 64 + 16 * i + lq * 4;
#pragma unroll
            for (int r = 0; r < 4; r++) {
                float v = acc[i][j][r] + bv;
                if constexpr (sizeof(OutT) == 2)
                    C[(size_t)(row0 + r) * N + col] = (OutT)f2bf(v);
                else
                    C[(size_t)(row0 + r) * N + col] = (OutT)v;
            }
        }
    }
}

// ---------------------------------------------------------------------------
// Fused long-conv pair via block-Toeplitz MFMA, one workgroup per channel d.
// ROUND-9 PROVEN FORM (117.4us, 128 VGPR, WRITE=32MB). FROZEN: every variant
// tried (occupancy 3blk r7, 8-ti r8, lag-1 dedup r10/r12, gpre on/off) was
// neutral-or-spilled; do not modify without a disasm-level diagnosis.
// ---------------------------------------------------------------------------
__global__ __launch_bounds__(512, 2) void conv_mfma(const ushort* __restrict__ At,
                                                    const ushort* __restrict__ X1t,
                                                    const float* __restrict__ kt,
                                                    const float* __restrict__ Db,
                                                    ushort* __restrict__ V2t, int nb) {
    __shared__ ushort a_lds[16 * 1024];   // 32 KB
    __shared__ ushort kc[8 * KCP];        // 17 KB, rebuilt per pass
    int d = blockIdx.x;
    int tid = threadIdx.x;
    int w = tid >> 6, l = tid & 63;
    int lr = l & 15, lq = l >> 4;

    // ---- stage a (16 batch rows; zeros for b >= nb) ----
    {
        int b = tid >> 5, s = tid & 31;
        const ushort* g = At + ((size_t)b * DMODEL + d) * LSEQ + s * 32;
#pragma unroll
        for (int j = 0; j < 4; j++) {       // 4 x 16B = 32 ushorts
            uint4 v = {0u, 0u, 0u, 0u};
            if (b < nb) v = *(const uint4*)(g + 8 * j);
            int byte = (b * 1024 + s * 32 + 8 * j) * 2;
            *(uint4*)((char*)a_lds + (byte ^ (b << 4))) = v;
        }
    }

    int p = (7 - lr) & 7;                  // lane parity (m,h-invariant)
    int v0 = 1023 - lr + 8 * lq - p;       // multiple of 8 -> 16B aligned
    int a_base = lr * 2048 + lq * 16;
    int swz = lr << 4;
    const int tis[4] = {w, 31 - w, 8 + w, 23 - w};  // 132 MFMA/wave/pass
    int ti0 = tis[0], ti1 = tis[1], ti2 = tis[2], ti3 = tis[3];

    // ---- prefetch gate x1 for the o==0 epilogue ----
    ushort gpre[4][2][4];
#pragma unroll
    for (int ii = 0; ii < 4; ii++)
#pragma unroll
        for (int h = 0; h < 2; h++)
#pragma unroll
            for (int r = 0; r < 4; r++) {
                int b = lq * 4 + r;
                int t2 = 32 * tis[ii] + 16 * h + lr;
                gpre[ii][h][r] = (b < nb)
                    ? X1t[((size_t)b * DMODEL + d) * LSEQ + t2] : (ushort)0;
            }

    for (int o = 0; o < 2; o++) {
        // ---- build reversed-shifted k copies for this order ----
        const float* krow = kt + ((size_t)o * DMODEL + d) * LSEQ;
        for (int idx = tid; idx < 8 * KCP; idx += 512) {
            int pp = idx / KCP;
            int u = idx - pp * KCP;
            int ki = 1023 - u - pp;
            kc[idx] = f2bf((ki >= 0) ? krow[ki] : 0.f);
        }
        __syncthreads();   // kc ready; prior a_lds writes visible

        f32x4 a00 = {}, a01 = {}, a10 = {}, a11 = {};
        f32x4 a20 = {}, a21 = {}, a30 = {}, a31 = {};
        const char* kbp = (const char*)kc + ((size_t)p * KCP + v0) * 2;
        for (int m = 0; m < 32; m++) {
            bf16x8 b0 = *(const bf16x8*)(kbp - 64 * m);        // h=0
            bf16x8 b1 = *(const bf16x8*)(kbp - 64 * m - 32);   // h=1
            __builtin_amdgcn_s_setprio(1);
#define CSTEP(TI, A0, A1)                                                      \
            if ((TI) >= m) {                                                   \
                bf16x8 af = *(const bf16x8*)((const char*)a_lds +              \
                                             ((a_base + 64 * ((TI) - m)) ^ swz)); \
                A0 = __builtin_amdgcn_mfma_f32_16x16x32_bf16(af, b0, A0, 0, 0, 0); \
                A1 = __builtin_amdgcn_mfma_f32_16x16x32_bf16(af, b1, A1, 0, 0, 0); \
            }
            CSTEP(ti0, a00, a01)
            CSTEP(ti1, a10, a11)
            CSTEP(ti2, a20, a21)
            CSTEP(ti3, a30, a31)
#undef CSTEP
            __builtin_amdgcn_s_setprio(0);
        }
        // ---- epilogue: each (b,t) cell read+written by exactly one lane ----
        float db = Db[o * DMODEL + d];
        __syncthreads();  // all MFMA reads of a_lds and kc complete
#define CEPI(II, TI, AC, H)                                                    \
        {                                                                      \
            _Pragma("unroll")                                                  \
            for (int r = 0; r < 4; r++) {                                      \
                int t2 = 32 * (TI) + 16 * (H) + lr;                            \
                int b = lq * 4 + r;                                            \
                int ab = ((b * 1024 + t2) * 2) ^ (b << 4);                     \
                float a0v = bf2f(*(const ushort*)((const char*)a_lds + ab));   \
                float y = (AC)[r] + a0v * db;                                  \
                if (o == 0) y *= bf2f(gpre[II][H][r]);                         \
                *(ushort*)((char*)a_lds + ab) = f2bf(y);                       \
            }                                                                  \
        }
        CEPI(0, ti0, a00, 0) CEPI(0, ti0, a01, 1)
        CEPI(1, ti1, a10, 0) CEPI(1, ti1, a11, 1)
        CEPI(2, ti2, a20, 0) CEPI(2, ti2, a21, 1)
        CEPI(3, ti3, a30, 0) CEPI(3, ti3, a31, 1)
#undef CEPI
        // next pass's pre-mfma __syncthreads publishes these a_lds writes
    }
    __syncthreads();  // publish o=1 epilogue writes for the writeout
    // ---- writeout ----
    {
        int b = tid >> 5, s = tid & 31;
        if (b < nb) {
            ushort* g = V2t + ((size_t)b * DMODEL + d) * LSEQ + s * 32;
#pragma unroll
            for (int j = 0; j < 4; j++) {   // 4 x 16B = 32 ushorts
                int byte = (b * 1024 + s * 32 + 8 * j) * 2;
                uint4 v = *(const uint4*)((const char*)a_lds + (byte ^ (b << 4)));
                *(uint4*)(g + 8 * j) = v;
            }
        }
    }
}

// ---------------------------------------------------------------------------
// Flat fp32 -> bf16 convert (4 elems/thread)
// ---------------------------------------------------------------------------
__global__ void cvt_bf16(const float* __restrict__ in, ushort* __restrict__ out, int n4) {
    int i = blockIdx.x * blockDim.x + threadIdx.x;
    if (i >= n4) return;
    float4 v = *(const float4*)&in[4 * i];
    uint2 pk;
    pk.x = (uint)f2bf(v.x) | ((uint)f2bf(v.y) << 16);
    pk.y = (uint)f2bf(v.z) | ((uint)f2bf(v.w) << 16);
    *(uint2*)&out[4 * i] = pk;
}

// ---------------------------------------------------------------------------
// Transpose + convert: in [R][C] fp32 -> out [C][R] bf16 (single z)
// ---------------------------------------------------------------------------
__global__ void transpose_cvt(const float* __restrict__ in, ushort* __restrict__ out,
                              int R, int C) {
    __shared__ float tile[32][33];
    int c0 = blockIdx.x * 32, r0 = blockIdx.y * 32;
    int tx = threadIdx.x, ty = threadIdx.y;
#pragma unroll
    for (int i = 0; i < 4; i++)
        tile[ty + 8 * i][tx] = in[(size_t)(r0 + ty + 8 * i) * C + c0 + tx];
    __syncthreads();
#pragma unroll
    for (int i = 0; i < 4; i++)
        out[(size_t)(c0 + ty + 8 * i) * R + r0 + tx] = f2bf(tile[tx][ty + 8 * i]);
}

// ---------------------------------------------------------------------------
// Per-batch bf16 transpose, uint-vectorized: in [b][D][L] -> out [b][L][D]
// ---------------------------------------------------------------------------
__global__ __launch_bounds__(256) void transpose_b16(const ushort* __restrict__ in,
                                                     ushort* __restrict__ out) {
    __shared__ uint tile[64][33];
    int t0 = blockIdx.x * 64, d0 = blockIdx.y * 64, b = blockIdx.z;
    int i = threadIdx.x;
    const ushort* ip = in + (size_t)b * DMODEL * LSEQ;
    ushort* op = out + (size_t)b * LSEQ * DMODEL;
    int dl = i >> 5, cu = i & 31;
#pragma unroll
    for (int j = 0; j < 8; j++)
        tile[dl + 8 * j][cu] =
            *(const uint*)&ip[(size_t)(d0 + dl + 8 * j) * LSEQ + t0 + 2 * cu];
    __syncthreads();
    int du = i & 31, tb = i >> 5;
#pragma unroll
    for (int j = 0; j < 8; j++) {
        int tl = tb + 8 * j;
        uint lo = (tile[2 * du][tl >> 1] >> (16 * (tl & 1))) & 0xFFFFu;
        uint hi = (tile[2 * du + 1][tl >> 1] >> (16 * (tl & 1))) & 0xFFFFu;
        *(uint*)&op[(size_t)(t0 + tl) * DMODEL + d0 + 2 * du] = lo | (hi << 16);
    }
}

// ---------------------------------------------------------------------------
// Parallel bias fuse (r12-proven: replaced a ~70us serial prep stall)
// ---------------------------------------------------------------------------
__global__ void bias_fuse_part(const float* __restrict__ bp,
                               const float* __restrict__ W_in,
                               float* __restrict__ partial) {
    int n = blockIdx.x * 256 + threadIdx.x;
    int k0 = blockIdx.y * 128;
    float s = 0.f;
    for (int k = k0; k < k0 + 128; k++) s += bp[k] * W_in[(size_t)k * D3 + n];
    partial[(size_t)blockIdx.y * D3 + n] = s;
}
__global__ void bias_fuse_red(const float* __restrict__ partial,
                              const float* __restrict__ b_in,
                              float* __restrict__ bf) {
    int n = blockIdx.x * 256 + threadIdx.x;
    float s = b_in[n];
#pragma unroll
    for (int j = 0; j < 8; j++) s += partial[(size_t)j * D3 + n];
    bf[n] = s;
}

// ---------------------------------------------------------------------------
// Transpose k_filt [2][L][D] fp32 -> kt [2][D][L] fp32
// ---------------------------------------------------------------------------
__global__ void transpose_k(const float* __restrict__ kf, float* __restrict__ kt) {
    __shared__ float tile[32][33];
    int s0 = blockIdx.x * 32, d0 = blockIdx.y * 32, o = blockIdx.z;
    int tx = threadIdx.x, ty = threadIdx.y;
#pragma unroll
    for (int i = 0; i < 4; i++)
        tile[ty + 8 * i][tx] = kf[((size_t)o * LSEQ + s0 + ty + 8 * i) * DMODEL + d0 + tx];
    __syncthreads();
#pragma unroll
    for (int i = 0; i < 4; i++)
        kt[((size_t)o * DMODEL + d0 + ty + 8 * i) * LSEQ + s0 + tx] = tile[tx][ty + 8 * i];
}

// ---------------------------------------------------------------------------
// Depthwise causal 3-tap conv on UC [cf,L,3D] bf16 + gating -> bf16 outputs.
// Channel-pair vectorized; all three channel-groups staged at once (1 barrier).
// grid (32, 16, cf), block (32,8)
// ---------------------------------------------------------------------------
__global__ __launch_bounds__(256) void shortconv_gate(const ushort* __restrict__ UC,
                                                      const float* __restrict__ sw,
                                                      const float* __restrict__ sb,
                                                      ushort* __restrict__ At,
                                                      ushort* __restrict__ X1t) {
    __shared__ uint tin[3][34][33];
    __shared__ ushort oA[64][34];
    __shared__ ushort oX[64][34];
    int t0 = blockIdx.x * 32, c0 = blockIdx.y * 64, b = blockIdx.z;
    int tx = threadIdx.x, ty = threadIdx.y;
#pragma unroll
    for (int g = 0; g < 3; g++) {
        int ch = g * DMODEL + c0 + 2 * tx;
        for (int r = ty; r < 34; r += 8) {
            int t = t0 + r - 2;
            tin[g][r][tx] = (t >= 0)
                ? *(const uint*)&UC[((size_t)b * LSEQ + t) * D3 + ch] : 0u;
        }
    }
    __syncthreads();
    float2 res[3][4];
#pragma unroll
    for (int g = 0; g < 3; g++) {
        int ch = g * DMODEL + c0 + 2 * tx;
        float w00 = sw[ch * 3 + 0], w01 = sw[ch * 3 + 1], w02 = sw[ch * 3 + 2];
        float w10 = sw[ch * 3 + 3], w11 = sw[ch * 3 + 4], w12 = sw[ch * 3 + 5];
        float bb0 = sb[ch], bb1 = sb[ch + 1];
#pragma unroll
        for (int i = 0; i < 4; i++) {
            int r = ty + 8 * i + 2;
            uint u0 = tin[g][r - 2][tx], u1 = tin[g][r - 1][tx], u2 = tin[g][r][tx];
            res[g][i].x = w00 * bf2f((ushort)u0) + w01 * bf2f((ushort)u1) +
                          w02 * bf2f((ushort)u2) + bb0;
            res[g][i].y = w10 * bf2f((ushort)(u0 >> 16)) + w11 * bf2f((ushort)(u1 >> 16)) +
                          w12 * bf2f((ushort)(u2 >> 16)) + bb1;
        }
    }
#pragma unroll
    for (int i = 0; i < 4; i++) {
        int t = ty + 8 * i;
        oA[2 * tx][t]     = f2bf(res[2][i].x * res[1][i].x);  // v * x2
        oA[2 * tx + 1][t] = f2bf(res[2][i].y * res[1][i].y);
        oX[2 * tx][t]     = f2bf(res[0][i].x);                // x1
        oX[2 * tx + 1][t] = f2bf(res[0][i].y);
    }
    __syncthreads();
    int li = ty * 32 + tx;              // 0..255
    int row = li >> 2, cu0 = (li & 3) * 4;
    ushort* gA = At  + ((size_t)b * DMODEL + c0 + row) * LSEQ + t0;
    ushort* gX = X1t + ((size_t)b * DMODEL + c0 + row) * LSEQ + t0;
#pragma unroll
    for (int j = 0; j < 4; j++) {
        int cu = cu0 + j;
        uint av = (uint)oA[row][2 * cu] | ((uint)oA[row][2 * cu + 1] << 16);
        uint xv = (uint)oX[row][2 * cu] | ((uint)oX[row][2 * cu + 1] << 16);
        *(uint*)&gA[2 * cu] = av;
        *(uint*)&gX[2 * cu] = xv;
    }
}

// ---------------------------------------------------------------------------
extern "C" void kernel_launch(void* const* d_in, const int* in_sizes, int n_in,
                              void* d_out, int out_size, void* d_ws, size_t ws_size,
                              hipStream_t stream) {
    (void)in_sizes; (void)n_in; (void)out_size;
    const float* x    = (const float*)d_in[0];
    const float* Wp   = (const float*)d_in[1];
    const float* bp   = (const float*)d_in[2];
    const float* W_in = (const float*)d_in[3];
    const float* b_in = (const float*)d_in[4];
    const float* sw   = (const float*)d_in[5];
    const float* sb   = (const float*)d_in[6];
    const float* kf   = (const float*)d_in[7];
    const float* Db   = (const float*)d_in[8];
    const float* Wout = (const float*)d_in[9];
    const float* bout = (const float*)d_in[10];
    float* out = (float*)d_out;

    char* ws = (char*)d_ws;
    // Persistent: Wf_t(3145728) bf(16384) kt(8388608) Wout_t(2097152)
    ushort* Wf_t   = (ushort*)(ws);
    float*  bfv    = (float*)(ws + 3145728);
    float*  kt     = (float*)(ws + 3162112);
    ushort* Wout_t = (ushort*)(ws + 11550720);
    const size_t PB = 13647872;

    // per-batch element sizes (bytes)
    const size_t XB  = 1048576;   // x_bf bf16
    const size_t ATB = 2097152;   // At bf16
    const size_t X1B = 2097152;   // X1t bf16
    const size_t UCB = 6291456;   // UC bf16 (1024*3072*2)
    const size_t V2B = 2097152;   // V2t / V2 bf16
    const size_t PREPB = 7471104; // W_inT + Wp_bf + bias partial scratch floor

    int cb = 1, cf = 1;
    {
        bool ok = false;
        for (int tcb = 16; tcb >= 1 && !ok; tcb >>= 1) {
            for (int tcf = tcb; tcf >= 1; tcf >>= 1) {
                size_t ucreg = (size_t)tcf * UCB;
                size_t v2need = (size_t)2 * tcb * V2B;
                if (ucreg < v2need) ucreg = v2need;
                if (ucreg < PREPB) ucreg = PREPB;
                size_t need = PB + (size_t)tcb * (XB + ATB + X1B) + ucreg;
                if (need <= ws_size) { cb = tcb; cf = tcf; ok = true; break; }
            }
        }
    }

    ushort* x_bf = (ushort*)(ws + PB);
    ushort* Atb  = (ushort*)(ws + PB + (size_t)cb * XB);
    ushort* X1tb = (ushort*)(ws + PB + (size_t)cb * (XB + ATB));
    char*   ucrg = ws + PB + (size_t)cb * (XB + ATB + X1B);
    ushort* UC   = (ushort*)ucrg;
    ushort* V2t  = (ushort*)ucrg;                         // UC dead by conv time
    ushort* V2   = (ushort*)(ucrg + (size_t)cb * V2B);
    // prep scratch aliases the UC region (used before UC is written)
    ushort* W_inT = (ushort*)ucrg;
    ushort* Wp_bf = (ushort*)(ucrg + 6291456);
    float*  bfp   = (float*)(ucrg + 7340032);             // 8x3072 fp32 partials

    // ---- one-time prep ----
    transpose_cvt<<<dim3(96, 32), dim3(32, 8), 0, stream>>>(W_in, W_inT, DMODEL, D3);
    cvt_bf16<<<512, 256, 0, stream>>>(Wp, Wp_bf, DIN * DMODEL / 4);
    gemm_mfma<ushort, false><<<dim3(4, 12), 512, 0, stream>>>(W_inT, Wp_bf, nullptr,
                                                              Wf_t, D3, DIN, DMODEL);
    bias_fuse_part<<<dim3(12, 8), 256, 0, stream>>>(bp, W_in, bfp);
    bias_fuse_red<<<12, 256, 0, stream>>>(bfp, b_in, bfv);
    transpose_cvt<<<dim3(32, 32), dim3(32, 8), 0, stream>>>(Wout, Wout_t, DMODEL, DMODEL);
    transpose_k<<<dim3(32, 32, 2), dim3(32, 8), 0, stream>>>(kf, kt);

    // ---- super-chunks of cb batches ----
    for (int b0 = 0; b0 < BATCH; b0 += cb) {
        cvt_bf16<<<cb * LSEQ * DIN / 1024, 256, 0, stream>>>(
            x + (size_t)b0 * LSEQ * DIN, x_bf, cb * LSEQ * DIN / 4);
        for (int f0 = 0; f0 < cb; f0 += cf) {
            // UC = x_bf @ Wf + bf   [cf*L, 3072] bf16
            gemm_mfma<ushort, true><<<dim3(24, cf * 4), 512, 0, stream>>>(
                x_bf + (size_t)f0 * LSEQ * DIN, Wf_t, bfv, UC, cf * LSEQ, D3, DIN);
            shortconv_gate<<<dim3(32, 16, cf), dim3(32, 8), 0, stream>>>(
                UC, sw, sb, Atb + (size_t)f0 * DMODEL * LSEQ,
                X1tb + (size_t)f0 * DMODEL * LSEQ);
        }
        // fused long-conv pair (block-Toeplitz MFMA), writes V2t bf16 [b][d][t]
        conv_mfma<<<DMODEL, 512, 0, stream>>>(Atb, X1tb, kt, Db, V2t, cb);
        // V2 [b][t][d] <- V2t [b][d][t]
        transpose_b16<<<dim3(16, 16, cb), dim3(256), 0, stream>>>(V2t, V2);
        // out = V2 @ W_out + b_out
        gemm_mfma<float, true><<<dim3(8, cb * 4), 512, 0, stream>>>(
            V2, Wout_t, bout, out + (size_t)b0 * LSEQ * DMODEL, cb * LSEQ, DMODEL, DMODEL);
    }
}

// Round 16
// 342.964 us; speedup vs baseline: 1.1371x; 1.1371x over previous
//
#include <hip/hip_runtime.h>

#define BATCH 16
#define LSEQ 1024
#define DIN 512
#define DMODEL 1024
#define D3 3072
#define KCP 1064  // padded stride of each reversed-k copy (2128B: all 8 copies distinct 16B phase mod 128B)

typedef __attribute__((ext_vector_type(4))) float f32x4;
typedef __attribute__((ext_vector_type(8))) short bf16x8;

static __device__ __forceinline__ ushort f2bf(float f) {
    uint u = __float_as_uint(f);
    return (ushort)((u + 0x7FFFu + ((u >> 16) & 1u)) >> 16);
}
static __device__ __forceinline__ float bf2f(ushort h) {
    return __uint_as_float(((uint)h) << 16);
}

#define GLD16(ldst, gsrc)                                                        \
    __builtin_amdgcn_global_load_lds(                                            \
        (const __attribute__((address_space(1))) void*)(gsrc),                   \
        (__attribute__((address_space(3))) void*)(ldst), 16, 0, 0)

// ---------------------------------------------------------------------------
// bf16 MFMA GEMM: C[M,N] = A[M,K]bf16 * B (as Bt[N,K]bf16) + bias.
// 256x128 tile, BK=32, 512 threads (8 waves = 4M x 2N), 4x4 16x16x32 frags
// per wave. Counted-vmcnt(3) double-buffer + XCD swizzle (nwg % 8 == 0).
// R12-PROVEN FORM (best measured: 340.2us total). Schedule variants all
// tested NEUTRAL-or-WORSE: 3-buffer deeper prefetch (r13: 0), single-barrier
// (r14: 0), coarse 2-phase split + swizzle (r15: -48us, 1 blk/CU + m196
// anti-pattern). Do not re-tune without the full 8-phase interleave port.
// ---------------------------------------------------------------------------
template <typename OutT, bool HAS_BIAS>
__global__ __launch_bounds__(512) void gemm_mfma(const ushort* __restrict__ A,
                                                 const ushort* __restrict__ Bt,
                                                 const float* __restrict__ bias,
                                                 OutT* __restrict__ C,
                                                 int M, int N, int K) {
    __shared__ ushort Als[2][256 * 32];   // 32 KB
    __shared__ ushort Bls[2][128 * 32];   // 16 KB
    int nwg = gridDim.x * gridDim.y;
    int bid = blockIdx.y * gridDim.x + blockIdx.x;
    bid = (bid & 7) * (nwg >> 3) + (bid >> 3);      // bijective: nwg % 8 == 0
    int n0 = (bid % gridDim.x) * 128, m0 = (bid / gridDim.x) * 256;
    int t = threadIdx.x;
    int w = t >> 6, l = t & 63;
    int wm = w >> 1, wn = w & 1;
    f32x4 acc[4][4] = {};

    int arow0 = 32 * w + (l >> 2);        // j=0 rows; j=1 adds 16
    int kpart = (l & 3) * 8;              // ushort offset within 32-k slab
    const ushort* gA0 = A + (size_t)(m0 + arow0) * K + kpart;
    const ushort* gA1 = gA0 + (size_t)16 * K;
    const ushort* gB0 = Bt + (size_t)(n0 + 16 * w + (l >> 2)) * K + kpart;
    int soA = 1024 * w;                   // wave-uniform ushort offsets
    int soB = 512 * w;

    int aoff = (wm * 64 + (l & 15)) * 32 + (l >> 4) * 8;
    int boff = (wn * 64 + (l & 15)) * 32 + (l >> 4) * 8;

    // prologue: stage slabs 0 and 1
    GLD16(&Als[0][soA], gA0);
    GLD16(&Als[0][soA + 512], gA1);
    GLD16(&Bls[0][soB], gB0);
    GLD16(&Als[1][soA], gA0 + 32);
    GLD16(&Als[1][soA + 512], gA1 + 32);
    GLD16(&Bls[1][soB], gB0 + 32);

    int cur = 0;
    for (int k0 = 0; k0 < K; k0 += 32) {
        // wait: cur slab's 3 loads landed; 3 newer may stay in flight
        if (k0 + 32 < K)
            asm volatile("s_waitcnt vmcnt(3)" ::: "memory");
        else
            asm volatile("s_waitcnt vmcnt(0)" ::: "memory");
        __builtin_amdgcn_s_barrier();
        __builtin_amdgcn_sched_barrier(0);
        bf16x8 af[4], bg[4];
#pragma unroll
        for (int i = 0; i < 4; i++) af[i] = *(const bf16x8*)&Als[cur][aoff + i * 512];
#pragma unroll
        for (int j = 0; j < 4; j++) bg[j] = *(const bf16x8*)&Bls[cur][boff + j * 512];
#pragma unroll
        for (int i = 0; i < 4; i++)
#pragma unroll
            for (int j = 0; j < 4; j++)
                acc[i][j] = __builtin_amdgcn_mfma_f32_16x16x32_bf16(af[i], bg[j],
                                                                    acc[i][j], 0, 0, 0);
        asm volatile("s_waitcnt lgkmcnt(0)" ::: "memory");
        __builtin_amdgcn_sched_barrier(0);
        __builtin_amdgcn_s_barrier();            // everyone done reading cur
        if (k0 + 64 < K) {                       // refill cur for slab k0+64
            GLD16(&Als[cur][soA], gA0 + k0 + 64);
            GLD16(&Als[cur][soA + 512], gA1 + k0 + 64);
            GLD16(&Bls[cur][soB], gB0 + k0 + 64);
        }
        cur ^= 1;
    }

#pragma unroll
    for (int j = 0; j < 4; j++) {
        int col = n0 + wn * 64 + 16 * j + (l & 15);
        float bv = HAS_BIAS ? bias[col] : 0.f;
#pragma unroll
        for (int i = 0; i < 4; i++) {
            int row0 = m0 + wm * 64 + 16 * i + (l >> 4) * 4;
#pragma unroll
            for (int r = 0; r < 4; r++) {
                float v = acc[i][j][r] + bv;
                if constexpr (sizeof(OutT) == 2)
                    C[(size_t)(row0 + r) * N + col] = (OutT)f2bf(v);
                else
                    C[(size_t)(row0 + r) * N + col] = (OutT)v;
            }
        }
    }
}

// ---------------------------------------------------------------------------
// Fused long-conv pair via block-Toeplitz MFMA, one workgroup per channel d.
// ROUND-9 PROVEN FORM (117.4us, 128 VGPR, WRITE=32MB). FROZEN: every variant
// (occupancy r7, 8-ti r8, lag-1 dedup r10/r12, gpre on/off) was neutral or
// spilled. Root cause understood r15: VGPR=128 is the 16-waves/CU boundary
// (m69) — ANY register increase halves occupancy/spills. Latency-bound at
// ~21% VALUBusy; fixing needs disasm-level ds_read pipelining within the
// 128-VGPR budget. Do not modify blind.
// ---------------------------------------------------------------------------
__global__ __launch_bounds__(512, 2) void conv_mfma(const ushort* __restrict__ At,
                                                    const ushort* __restrict__ X1t,
                                                    const float* __restrict__ kt,
                                                    const float* __restrict__ Db,
                                                    ushort* __restrict__ V2t, int nb) {
    __shared__ ushort a_lds[16 * 1024];   // 32 KB
    __shared__ ushort kc[8 * KCP];        // 17 KB, rebuilt per pass
    int d = blockIdx.x;
    int tid = threadIdx.x;
    int w = tid >> 6, l = tid & 63;
    int lr = l & 15, lq = l >> 4;

    // ---- stage a (16 batch rows; zeros for b >= nb) ----
    {
        int b = tid >> 5, s = tid & 31;
        const ushort* g = At + ((size_t)b * DMODEL + d) * LSEQ + s * 32;
#pragma unroll
        for (int j = 0; j < 4; j++) {       // 4 x 16B = 32 ushorts
            uint4 v = {0u, 0u, 0u, 0u};
            if (b < nb) v = *(const uint4*)(g + 8 * j);
            int byte = (b * 1024 + s * 32 + 8 * j) * 2;
            *(uint4*)((char*)a_lds + (byte ^ (b << 4))) = v;
        }
    }

    int p = (7 - lr) & 7;                  // lane parity (m,h-invariant)
    int v0 = 1023 - lr + 8 * lq - p;       // multiple of 8 -> 16B aligned
    int a_base = lr * 2048 + lq * 16;
    int swz = lr << 4;
    const int tis[4] = {w, 31 - w, 8 + w, 23 - w};  // 132 MFMA/wave/pass
    int ti0 = tis[0], ti1 = tis[1], ti2 = tis[2], ti3 = tis[3];

    // ---- prefetch gate x1 for the o==0 epilogue ----
    ushort gpre[4][2][4];
#pragma unroll
    for (int ii = 0; ii < 4; ii++)
#pragma unroll
        for (int h = 0; h < 2; h++)
#pragma unroll
            for (int r = 0; r < 4; r++) {
                int b = lq * 4 + r;
                int t2 = 32 * tis[ii] + 16 * h + lr;
                gpre[ii][h][r] = (b < nb)
                    ? X1t[((size_t)b * DMODEL + d) * LSEQ + t2] : (ushort)0;
            }

    for (int o = 0; o < 2; o++) {
        // ---- build reversed-shifted k copies for this order ----
        const float* krow = kt + ((size_t)o * DMODEL + d) * LSEQ;
        for (int idx = tid; idx < 8 * KCP; idx += 512) {
            int pp = idx / KCP;
            int u = idx - pp * KCP;
            int ki = 1023 - u - pp;
            kc[idx] = f2bf((ki >= 0) ? krow[ki] : 0.f);
        }
        __syncthreads();   // kc ready; prior a_lds writes visible

        f32x4 a00 = {}, a01 = {}, a10 = {}, a11 = {};
        f32x4 a20 = {}, a21 = {}, a30 = {}, a31 = {};
        const char* kbp = (const char*)kc + ((size_t)p * KCP + v0) * 2;
        for (int m = 0; m < 32; m++) {
            bf16x8 b0 = *(const bf16x8*)(kbp - 64 * m);        // h=0
            bf16x8 b1 = *(const bf16x8*)(kbp - 64 * m - 32);   // h=1
            __builtin_amdgcn_s_setprio(1);
#define CSTEP(TI, A0, A1)                                                      \
            if ((TI) >= m) {                                                   \
                bf16x8 af = *(const bf16x8*)((const char*)a_lds +              \
                                             ((a_base + 64 * ((TI) - m)) ^ swz)); \
                A0 = __builtin_amdgcn_mfma_f32_16x16x32_bf16(af, b0, A0, 0, 0, 0); \
                A1 = __builtin_amdgcn_mfma_f32_16x16x32_bf16(af, b1, A1, 0, 0, 0); \
            }
            CSTEP(ti0, a00, a01)
            CSTEP(ti1, a10, a11)
            CSTEP(ti2, a20, a21)
            CSTEP(ti3, a30, a31)
#undef CSTEP
            __builtin_amdgcn_s_setprio(0);
        }
        // ---- epilogue: each (b,t) cell read+written by exactly one lane ----
        float db = Db[o * DMODEL + d];
        __syncthreads();  // all MFMA reads of a_lds and kc complete
#define CEPI(II, TI, AC, H)                                                    \
        {                                                                      \
            _Pragma("unroll")                                                  \
            for (int r = 0; r < 4; r++) {                                      \
                int t2 = 32 * (TI) + 16 * (H) + lr;                            \
                int b = lq * 4 + r;                                            \
                int ab = ((b * 1024 + t2) * 2) ^ (b << 4);                     \
                float a0v = bf2f(*(const ushort*)((const char*)a_lds + ab));   \
                float y = (AC)[r] + a0v * db;                                  \
                if (o == 0) y *= bf2f(gpre[II][H][r]);                         \
                *(ushort*)((char*)a_lds + ab) = f2bf(y);                       \
            }                                                                  \
        }
        CEPI(0, ti0, a00, 0) CEPI(0, ti0, a01, 1)
        CEPI(1, ti1, a10, 0) CEPI(1, ti1, a11, 1)
        CEPI(2, ti2, a20, 0) CEPI(2, ti2, a21, 1)
        CEPI(3, ti3, a30, 0) CEPI(3, ti3, a31, 1)
#undef CEPI
        // next pass's pre-mfma __syncthreads publishes these a_lds writes
    }
    __syncthreads();  // publish o=1 epilogue writes for the writeout
    // ---- writeout ----
    {
        int b = tid >> 5, s = tid & 31;
        if (b < nb) {
            ushort* g = V2t + ((size_t)b * DMODEL + d) * LSEQ + s * 32;
#pragma unroll
            for (int j = 0; j < 4; j++) {   // 4 x 16B = 32 ushorts
                int byte = (b * 1024 + s * 32 + 8 * j) * 2;
                uint4 v = *(const uint4*)((const char*)a_lds + (byte ^ (b << 4)));
                *(uint4*)(g + 8 * j) = v;
            }
        }
    }
}

// ---------------------------------------------------------------------------
// Flat fp32 -> bf16 convert (4 elems/thread)
// ---------------------------------------------------------------------------
__global__ void cvt_bf16(const float* __restrict__ in, ushort* __restrict__ out, int n4) {
    int i = blockIdx.x * blockDim.x + threadIdx.x;
    if (i >= n4) return;
    float4 v = *(const float4*)&in[4 * i];
    uint2 pk;
    pk.x = (uint)f2bf(v.x) | ((uint)f2bf(v.y) << 16);
    pk.y = (uint)f2bf(v.z) | ((uint)f2bf(v.w) << 16);
    *(uint2*)&out[4 * i] = pk;
}

// ---------------------------------------------------------------------------
// Transpose + convert: in [R][C] fp32 -> out [C][R] bf16 (single z)
// ---------------------------------------------------------------------------
__global__ void transpose_cvt(const float* __restrict__ in, ushort* __restrict__ out,
                              int R, int C) {
    __shared__ float tile[32][33];
    int c0 = blockIdx.x * 32, r0 = blockIdx.y * 32;
    int tx = threadIdx.x, ty = threadIdx.y;
#pragma unroll
    for (int i = 0; i < 4; i++)
        tile[ty + 8 * i][tx] = in[(size_t)(r0 + ty + 8 * i) * C + c0 + tx];
    __syncthreads();
#pragma unroll
    for (int i = 0; i < 4; i++)
        out[(size_t)(c0 + ty + 8 * i) * R + r0 + tx] = f2bf(tile[tx][ty + 8 * i]);
}

// ---------------------------------------------------------------------------
// Per-batch bf16 transpose, uint-vectorized: in [b][D][L] -> out [b][L][D]
// ---------------------------------------------------------------------------
__global__ __launch_bounds__(256) void transpose_b16(const ushort* __restrict__ in,
                                                     ushort* __restrict__ out) {
    __shared__ uint tile[64][33];
    int t0 = blockIdx.x * 64, d0 = blockIdx.y * 64, b = blockIdx.z;
    int i = threadIdx.x;
    const ushort* ip = in + (size_t)b * DMODEL * LSEQ;
    ushort* op = out + (size_t)b * LSEQ * DMODEL;
    int dl = i >> 5, cu = i & 31;
#pragma unroll
    for (int j = 0; j < 8; j++)
        tile[dl + 8 * j][cu] =
            *(const uint*)&ip[(size_t)(d0 + dl + 8 * j) * LSEQ + t0 + 2 * cu];
    __syncthreads();
    int du = i & 31, tb = i >> 5;
#pragma unroll
    for (int j = 0; j < 8; j++) {
        int tl = tb + 8 * j;
        uint lo = (tile[2 * du][tl >> 1] >> (16 * (tl & 1))) & 0xFFFFu;
        uint hi = (tile[2 * du + 1][tl >> 1] >> (16 * (tl & 1))) & 0xFFFFu;
        *(uint*)&op[(size_t)(t0 + tl) * DMODEL + d0 + 2 * du] = lo | (hi << 16);
    }
}

// ---------------------------------------------------------------------------
// Parallel bias fuse (r12-proven: replaced a ~70us serial prep stall)
// ---------------------------------------------------------------------------
__global__ void bias_fuse_part(const float* __restrict__ bp,
                               const float* __restrict__ W_in,
                               float* __restrict__ partial) {
    int n = blockIdx.x * 256 + threadIdx.x;
    int k0 = blockIdx.y * 128;
    float s = 0.f;
    for (int k = k0; k < k0 + 128; k++) s += bp[k] * W_in[(size_t)k * D3 + n];
    partial[(size_t)blockIdx.y * D3 + n] = s;
}
__global__ void bias_fuse_red(const float* __restrict__ partial,
                              const float* __restrict__ b_in,
                              float* __restrict__ bf) {
    int n = blockIdx.x * 256 + threadIdx.x;
    float s = b_in[n];
#pragma unroll
    for (int j = 0; j < 8; j++) s += partial[(size_t)j * D3 + n];
    bf[n] = s;
}

// ---------------------------------------------------------------------------
// Transpose k_filt [2][L][D] fp32 -> kt [2][D][L] fp32
// ---------------------------------------------------------------------------
__global__ void transpose_k(const float* __restrict__ kf, float* __restrict__ kt) {
    __shared__ float tile[32][33];
    int s0 = blockIdx.x * 32, d0 = blockIdx.y * 32, o = blockIdx.z;
    int tx = threadIdx.x, ty = threadIdx.y;
#pragma unroll
    for (int i = 0; i < 4; i++)
        tile[ty + 8 * i][tx] = kf[((size_t)o * LSEQ + s0 + ty + 8 * i) * DMODEL + d0 + tx];
    __syncthreads();
#pragma unroll
    for (int i = 0; i < 4; i++)
        kt[((size_t)o * DMODEL + d0 + ty + 8 * i) * LSEQ + s0 + tx] = tile[tx][ty + 8 * i];
}

// ---------------------------------------------------------------------------
// Depthwise causal 3-tap conv on UC [cf,L,3D] bf16 + gating -> bf16 outputs.
// Channel-pair vectorized; all three channel-groups staged at once (1 barrier).
// grid (32, 16, cf), block (32,8)
// ---------------------------------------------------------------------------
__global__ __launch_bounds__(256) void shortconv_gate(const ushort* __restrict__ UC,
                                                      const float* __restrict__ sw,
                                                      const float* __restrict__ sb,
                                                      ushort* __restrict__ At,
                                                      ushort* __restrict__ X1t) {
    __shared__ uint tin[3][34][33];
    __shared__ ushort oA[64][34];
    __shared__ ushort oX[64][34];
    int t0 = blockIdx.x * 32, c0 = blockIdx.y * 64, b = blockIdx.z;
    int tx = threadIdx.x, ty = threadIdx.y;
#pragma unroll
    for (int g = 0; g < 3; g++) {
        int ch = g * DMODEL + c0 + 2 * tx;
        for (int r = ty; r < 34; r += 8) {
            int t = t0 + r - 2;
            tin[g][r][tx] = (t >= 0)
                ? *(const uint*)&UC[((size_t)b * LSEQ + t) * D3 + ch] : 0u;
        }
    }
    __syncthreads();
    float2 res[3][4];
#pragma unroll
    for (int g = 0; g < 3; g++) {
        int ch = g * DMODEL + c0 + 2 * tx;
        float w00 = sw[ch * 3 + 0], w01 = sw[ch * 3 + 1], w02 = sw[ch * 3 + 2];
        float w10 = sw[ch * 3 + 3], w11 = sw[ch * 3 + 4], w12 = sw[ch * 3 + 5];
        float bb0 = sb[ch], bb1 = sb[ch + 1];
#pragma unroll
        for (int i = 0; i < 4; i++) {
            int r = ty + 8 * i + 2;
            uint u0 = tin[g][r - 2][tx], u1 = tin[g][r - 1][tx], u2 = tin[g][r][tx];
            res[g][i].x = w00 * bf2f((ushort)u0) + w01 * bf2f((ushort)u1) +
                          w02 * bf2f((ushort)u2) + bb0;
            res[g][i].y = w10 * bf2f((ushort)(u0 >> 16)) + w11 * bf2f((ushort)(u1 >> 16)) +
                          w12 * bf2f((ushort)(u2 >> 16)) + bb1;
        }
    }
#pragma unroll
    for (int i = 0; i < 4; i++) {
        int t = ty + 8 * i;
        oA[2 * tx][t]     = f2bf(res[2][i].x * res[1][i].x);  // v * x2
        oA[2 * tx + 1][t] = f2bf(res[2][i].y * res[1][i].y);
        oX[2 * tx][t]     = f2bf(res[0][i].x);                // x1
        oX[2 * tx + 1][t] = f2bf(res[0][i].y);
    }
    __syncthreads();
    int li = ty * 32 + tx;              // 0..255
    int row = li >> 2, cu0 = (li & 3) * 4;
    ushort* gA = At  + ((size_t)b * DMODEL + c0 + row) * LSEQ + t0;
    ushort* gX = X1t + ((size_t)b * DMODEL + c0 + row) * LSEQ + t0;
#pragma unroll
    for (int j = 0; j < 4; j++) {
        int cu = cu0 + j;
        uint av = (uint)oA[row][2 * cu] | ((uint)oA[row][2 * cu + 1] << 16);
        uint xv = (uint)oX[row][2 * cu] | ((uint)oX[row][2 * cu + 1] << 16);
        *(uint*)&gA[2 * cu] = av;
        *(uint*)&gX[2 * cu] = xv;
    }
}

// ---------------------------------------------------------------------------
extern "C" void kernel_launch(void* const* d_in, const int* in_sizes, int n_in,
                              void* d_out, int out_size, void* d_ws, size_t ws_size,
                              hipStream_t stream) {
    (void)in_sizes; (void)n_in; (void)out_size;
    const float* x    = (const float*)d_in[0];
    const float* Wp   = (const float*)d_in[1];
    const float* bp   = (const float*)d_in[2];
    const float* W_in = (const float*)d_in[3];
    const float* b_in = (const float*)d_in[4];
    const float* sw   = (const float*)d_in[5];
    const float* sb   = (const float*)d_in[6];
    const float* kf   = (const float*)d_in[7];
    const float* Db   = (const float*)d_in[8];
    const float* Wout = (const float*)d_in[9];
    const float* bout = (const float*)d_in[10];
    float* out = (float*)d_out;

    char* ws = (char*)d_ws;
    // Persistent: Wf_t(3145728) bf(16384) kt(8388608) Wout_t(2097152)
    ushort* Wf_t   = (ushort*)(ws);
    float*  bfv    = (float*)(ws + 3145728);
    float*  kt     = (float*)(ws + 3162112);
    ushort* Wout_t = (ushort*)(ws + 11550720);
    const size_t PB = 13647872;

    // per-batch element sizes (bytes)
    const size_t XB  = 1048576;   // x_bf bf16
    const size_t ATB = 2097152;   // At bf16
    const size_t X1B = 2097152;   // X1t bf16
    const size_t UCB = 6291456;   // UC bf16 (1024*3072*2)
    const size_t V2B = 2097152;   // V2t / V2 bf16
    const size_t PREPB = 7471104; // W_inT + Wp_bf + bias partial scratch floor

    int cb = 1, cf = 1;
    {
        bool ok = false;
        for (int tcb = 16; tcb >= 1 && !ok; tcb >>= 1) {
            for (int tcf = tcb; tcf >= 1; tcf >>= 1) {
                size_t ucreg = (size_t)tcf * UCB;
                size_t v2need = (size_t)2 * tcb * V2B;
                if (ucreg < v2need) ucreg = v2need;
                if (ucreg < PREPB) ucreg = PREPB;
                size_t need = PB + (size_t)tcb * (XB + ATB + X1B) + ucreg;
                if (need <= ws_size) { cb = tcb; cf = tcf; ok = true; break; }
            }
        }
    }

    ushort* x_bf = (ushort*)(ws + PB);
    ushort* Atb  = (ushort*)(ws + PB + (size_t)cb * XB);
    ushort* X1tb = (ushort*)(ws + PB + (size_t)cb * (XB + ATB));
    char*   ucrg = ws + PB + (size_t)cb * (XB + ATB + X1B);
    ushort* UC   = (ushort*)ucrg;
    ushort* V2t  = (ushort*)ucrg;                         // UC dead by conv time
    ushort* V2   = (ushort*)(ucrg + (size_t)cb * V2B);
    // prep scratch aliases the UC region (used before UC is written)
    ushort* W_inT = (ushort*)ucrg;
    ushort* Wp_bf = (ushort*)(ucrg + 6291456);
    float*  bfp   = (float*)(ucrg + 7340032);             // 8x3072 fp32 partials

    // ---- one-time prep ----
    transpose_cvt<<<dim3(96, 32), dim3(32, 8), 0, stream>>>(W_in, W_inT, DMODEL, D3);
    cvt_bf16<<<512, 256, 0, stream>>>(Wp, Wp_bf, DIN * DMODEL / 4);
    gemm_mfma<ushort, false><<<dim3(4, 12), 512, 0, stream>>>(W_inT, Wp_bf, nullptr,
                                                              Wf_t, D3, DIN, DMODEL);
    bias_fuse_part<<<dim3(12, 8), 256, 0, stream>>>(bp, W_in, bfp);
    bias_fuse_red<<<12, 256, 0, stream>>>(bfp, b_in, bfv);
    transpose_cvt<<<dim3(32, 32), dim3(32, 8), 0, stream>>>(Wout, Wout_t, DMODEL, DMODEL);
    transpose_k<<<dim3(32, 32, 2), dim3(32, 8), 0, stream>>>(kf, kt);

    // ---- super-chunks of cb batches ----
    for (int b0 = 0; b0 < BATCH; b0 += cb) {
        cvt_bf16<<<cb * LSEQ * DIN / 1024, 256, 0, stream>>>(
            x + (size_t)b0 * LSEQ * DIN, x_bf, cb * LSEQ * DIN / 4);
        for (int f0 = 0; f0 < cb; f0 += cf) {
            // UC = x_bf @ Wf + bf   [cf*L, 3072] bf16
            gemm_mfma<ushort, true><<<dim3(24, cf * 4), 512, 0, stream>>>(
                x_bf + (size_t)f0 * LSEQ * DIN, Wf_t, bfv, UC, cf * LSEQ, D3, DIN);
            shortconv_gate<<<dim3(32, 16, cf), dim3(32, 8), 0, stream>>>(
                UC, sw, sb, Atb + (size_t)f0 * DMODEL * LSEQ,
                X1tb + (size_t)f0 * DMODEL * LSEQ);
        }
        // fused long-conv pair (block-Toeplitz MFMA), writes V2t bf16 [b][d][t]
        conv_mfma<<<DMODEL, 512, 0, stream>>>(Atb, X1tb, kt, Db, V2t, cb);
        // V2 [b][t][d] <- V2t [b][d][t]
        transpose_b16<<<dim3(16, 16, cb), dim3(256), 0, stream>>>(V2t, V2);
        // out = V2 @ W_out + b_out
        gemm_mfma<float, true><<<dim3(8, cb * 4), 512, 0, stream>>>(
            V2, Wout_t, bout, out + (size_t)b0 * LSEQ * DMODEL, cb * LSEQ, DMODEL, DMODEL);
    }
}

// Round 18
// 335.266 us; speedup vs baseline: 1.1632x; 1.0230x over previous
//
#include <hip/hip_runtime.h>

#define BATCH 16
#define LSEQ 1024
#define DIN 512
#define DMODEL 1024
#define D3 3072
#define KCP 1064  // padded stride of each reversed-k copy (2128B: all 8 copies distinct 16B phase mod 128B)

typedef __attribute__((ext_vector_type(4))) float f32x4;
typedef __attribute__((ext_vector_type(8))) short bf16x8;

static __device__ __forceinline__ ushort f2bf(float f) {
    uint u = __float_as_uint(f);
    return (ushort)((u + 0x7FFFu + ((u >> 16) & 1u)) >> 16);
}
static __device__ __forceinline__ float bf2f(ushort h) {
    return __uint_as_float(((uint)h) << 16);
}

#define GLD16(ldst, gsrc)                                                        \
    __builtin_amdgcn_global_load_lds(                                            \
        (const __attribute__((address_space(1))) void*)(gsrc),                   \
        (__attribute__((address_space(3))) void*)(ldst), 16, 0, 0)

// ---------------------------------------------------------------------------
// bf16 MFMA GEMM: C[M,N] = A[M,K]bf16 * B (as Bt[N,K]bf16) + bias.
// 256x128 tile, BK=32, 512 threads (8 waves = 4M x 2N), 4x4 16x16x32 frags
// per wave. Counted-vmcnt(3) double-buffer + XCD swizzle (nwg % 8 == 0).
// R12-PROVEN FORM (best measured). Schedule variants all tested
// NEUTRAL-or-WORSE: 3-buffer prefetch (r13), single-barrier (r14), coarse
// 2-phase split (r15: -48us). Do not re-tune without a full 8-phase port.
// ---------------------------------------------------------------------------
template <typename OutT, bool HAS_BIAS>
__global__ __launch_bounds__(512) void gemm_mfma(const ushort* __restrict__ A,
                                                 const ushort* __restrict__ Bt,
                                                 const float* __restrict__ bias,
                                                 OutT* __restrict__ C,
                                                 int M, int N, int K) {
    __shared__ ushort Als[2][256 * 32];   // 32 KB
    __shared__ ushort Bls[2][128 * 32];   // 16 KB
    int nwg = gridDim.x * gridDim.y;
    int bid = blockIdx.y * gridDim.x + blockIdx.x;
    bid = (bid & 7) * (nwg >> 3) + (bid >> 3);      // bijective: nwg % 8 == 0
    int n0 = (bid % gridDim.x) * 128, m0 = (bid / gridDim.x) * 256;
    int t = threadIdx.x;
    int w = t >> 6, l = t & 63;
    int wm = w >> 1, wn = w & 1;
    f32x4 acc[4][4] = {};

    int arow0 = 32 * w + (l >> 2);        // j=0 rows; j=1 adds 16
    int kpart = (l & 3) * 8;              // ushort offset within 32-k slab
    const ushort* gA0 = A + (size_t)(m0 + arow0) * K + kpart;
    const ushort* gA1 = gA0 + (size_t)16 * K;
    const ushort* gB0 = Bt + (size_t)(n0 + 16 * w + (l >> 2)) * K + kpart;
    int soA = 1024 * w;                   // wave-uniform ushort offsets
    int soB = 512 * w;

    int aoff = (wm * 64 + (l & 15)) * 32 + (l >> 4) * 8;
    int boff = (wn * 64 + (l & 15)) * 32 + (l >> 4) * 8;

    // prologue: stage slabs 0 and 1
    GLD16(&Als[0][soA], gA0);
    GLD16(&Als[0][soA + 512], gA1);
    GLD16(&Bls[0][soB], gB0);
    GLD16(&Als[1][soA], gA0 + 32);
    GLD16(&Als[1][soA + 512], gA1 + 32);
    GLD16(&Bls[1][soB], gB0 + 32);

    int cur = 0;
    for (int k0 = 0; k0 < K; k0 += 32) {
        // wait: cur slab's 3 loads landed; 3 newer may stay in flight
        if (k0 + 32 < K)
            asm volatile("s_waitcnt vmcnt(3)" ::: "memory");
        else
            asm volatile("s_waitcnt vmcnt(0)" ::: "memory");
        __builtin_amdgcn_s_barrier();
        __builtin_amdgcn_sched_barrier(0);
        bf16x8 af[4], bg[4];
#pragma unroll
        for (int i = 0; i < 4; i++) af[i] = *(const bf16x8*)&Als[cur][aoff + i * 512];
#pragma unroll
        for (int j = 0; j < 4; j++) bg[j] = *(const bf16x8*)&Bls[cur][boff + j * 512];
#pragma unroll
        for (int i = 0; i < 4; i++)
#pragma unroll
            for (int j = 0; j < 4; j++)
                acc[i][j] = __builtin_amdgcn_mfma_f32_16x16x32_bf16(af[i], bg[j],
                                                                    acc[i][j], 0, 0, 0);
        asm volatile("s_waitcnt lgkmcnt(0)" ::: "memory");
        __builtin_amdgcn_sched_barrier(0);
        __builtin_amdgcn_s_barrier();            // everyone done reading cur
        if (k0 + 64 < K) {                       // refill cur for slab k0+64
            GLD16(&Als[cur][soA], gA0 + k0 + 64);
            GLD16(&Als[cur][soA + 512], gA1 + k0 + 64);
            GLD16(&Bls[cur][soB], gB0 + k0 + 64);
        }
        cur ^= 1;
    }

#pragma unroll
    for (int j = 0; j < 4; j++) {
        int col = n0 + wn * 64 + 16 * j + (l & 15);
        float bv = HAS_BIAS ? bias[col] : 0.f;
#pragma unroll
        for (int i = 0; i < 4; i++) {
            int row0 = m0 + wm * 64 + 16 * i + (l >> 4) * 4;
#pragma unroll
            for (int r = 0; r < 4; r++) {
                float v = acc[i][j][r] + bv;
                if constexpr (sizeof(OutT) == 2)
                    C[(size_t)(row0 + r) * N + col] = (OutT)f2bf(v);
                else
                    C[(size_t)(row0 + r) * N + col] = (OutT)v;
            }
        }
    }
}

// ---------------------------------------------------------------------------
// Small-tile bf16 GEMM for the tiny prep matmul (Wf_t = W_inT @ Wp_bf):
// 64x64 tile, ONE wave/block -> grid 8x48 = 384 blocks (the 256x128 kernel
// gave only 48 blocks = 19% machine utilization — same tiny-grid-stall class
// as the r12 bias_fuse fix). Same fragment math and K-order as gemm_mfma
// (wm=wn=0) -> bit-identical Wf_t. Both A and B tiles are row-major [64][32],
// so the B fragment base equals the A one (aoff + j*512). Counted vmcnt(8)
// double buffer; no s_barrier (wave-synchronous); lgkmcnt(0) before refill.
// ---------------------------------------------------------------------------
__global__ __launch_bounds__(64) void gemm_small(const ushort* __restrict__ A,
                                                 const ushort* __restrict__ Bt,
                                                 ushort* __restrict__ C,
                                                 int M, int N, int K) {
    __shared__ ushort Als[2][64 * 32];    // 8 KB
    __shared__ ushort Bls[2][64 * 32];    // 8 KB
    int n0 = blockIdx.x * 64, m0 = blockIdx.y * 64;
    int l = threadIdx.x;
    int lr = l & 15, lq = l >> 4;
    f32x4 acc[4][4] = {};

    int row = l >> 2;                     // staging row within 16-row group
    int kp = (l & 3) * 8;
    const ushort* gA = A + (size_t)(m0 + row) * K + kp;
    const ushort* gB = Bt + (size_t)(n0 + row) * K + kp;

    int aoff = lr * 32 + lq * 8;          // fragment base (row-major 64x32)

    // prologue: stage slabs 0 and 1 (8 GLD16 each)
#pragma unroll
    for (int j = 0; j < 4; j++) {
        GLD16(&Als[0][512 * j], gA + (size_t)16 * j * K);
        GLD16(&Bls[0][512 * j], gB + (size_t)16 * j * K);
    }
#pragma unroll
    for (int j = 0; j < 4; j++) {
        GLD16(&Als[1][512 * j], gA + (size_t)16 * j * K + 32);
        GLD16(&Bls[1][512 * j], gB + (size_t)16 * j * K + 32);
    }

    int cur = 0;
    for (int k0 = 0; k0 < K; k0 += 32) {
        if (k0 + 32 < K)
            asm volatile("s_waitcnt vmcnt(8)" ::: "memory");  // cur's 8 landed
        else
            asm volatile("s_waitcnt vmcnt(0)" ::: "memory");
        __builtin_amdgcn_sched_barrier(0);
        bf16x8 af[4], bg[4];
#pragma unroll
        for (int i = 0; i < 4; i++) af[i] = *(const bf16x8*)&Als[cur][aoff + i * 512];
#pragma unroll
        for (int j = 0; j < 4; j++) bg[j] = *(const bf16x8*)&Bls[cur][aoff + j * 512];
#pragma unroll
        for (int i = 0; i < 4; i++)
#pragma unroll
            for (int j = 0; j < 4; j++)
                acc[i][j] = __builtin_amdgcn_mfma_f32_16x16x32_bf16(af[i], bg[j],
                                                                    acc[i][j], 0, 0, 0);
        asm volatile("s_waitcnt lgkmcnt(0)" ::: "memory");    // frag reads done
        __builtin_amdgcn_sched_barrier(0);
        if (k0 + 64 < K) {
#pragma unroll
            for (int j = 0; j < 4; j++) {
                GLD16(&Als[cur][512 * j], gA + (size_t)16 * j * K + k0 + 64);
                GLD16(&Bls[cur][512 * j], gB + (size_t)16 * j * K + k0 + 64);
            }
        }
        cur ^= 1;
    }

#pragma unroll
    for (int j = 0; j < 4; j++) {
        int col = n0 + 16 * j + lr;
#pragma unroll
        for (int i = 0; i < 4; i++) {
            int row0 = m0 + 16 * i + lq * 4;
#pragma unroll
            for (int r = 0; r < 4; r++)
                C[(size_t)(row0 + r) * N + col] = f2bf(acc[i][j][r]);
        }
    }
}

// ---------------------------------------------------------------------------
// Fused long-conv pair via block-Toeplitz MFMA, one workgroup per channel d.
// ROUND-9 PROVEN FORM (117.4us, 128 VGPR, WRITE=32MB). FROZEN: every variant
// (occupancy r7, 8-ti r8, lag-1 dedup r10/r12, gpre on/off) was neutral or
// spilled. VGPR=128 is the 16-waves/CU boundary (m69) — any register
// increase spills. Latency-bound; needs disasm-level work. Do not modify.
// ---------------------------------------------------------------------------
__global__ __launch_bounds__(512, 2) void conv_mfma(const ushort* __restrict__ At,
                                                    const ushort* __restrict__ X1t,
                                                    const float* __restrict__ kt,
                                                    const float* __restrict__ Db,
                                                    ushort* __restrict__ V2t, int nb) {
    __shared__ ushort a_lds[16 * 1024];   // 32 KB
    __shared__ ushort kc[8 * KCP];        // 17 KB, rebuilt per pass
    int d = blockIdx.x;
    int tid = threadIdx.x;
    int w = tid >> 6, l = tid & 63;
    int lr = l & 15, lq = l >> 4;

    // ---- stage a (16 batch rows; zeros for b >= nb) ----
    {
        int b = tid >> 5, s = tid & 31;
        const ushort* g = At + ((size_t)b * DMODEL + d) * LSEQ + s * 32;
#pragma unroll
        for (int j = 0; j < 4; j++) {       // 4 x 16B = 32 ushorts
            uint4 v = {0u, 0u, 0u, 0u};
            if (b < nb) v = *(const uint4*)(g + 8 * j);
            int byte = (b * 1024 + s * 32 + 8 * j) * 2;
            *(uint4*)((char*)a_lds + (byte ^ (b << 4))) = v;
        }
    }

    int p = (7 - lr) & 7;                  // lane parity (m,h-invariant)
    int v0 = 1023 - lr + 8 * lq - p;       // multiple of 8 -> 16B aligned
    int a_base = lr * 2048 + lq * 16;
    int swz = lr << 4;
    const int tis[4] = {w, 31 - w, 8 + w, 23 - w};  // 132 MFMA/wave/pass
    int ti0 = tis[0], ti1 = tis[1], ti2 = tis[2], ti3 = tis[3];

    // ---- prefetch gate x1 for the o==0 epilogue ----
    ushort gpre[4][2][4];
#pragma unroll
    for (int ii = 0; ii < 4; ii++)
#pragma unroll
        for (int h = 0; h < 2; h++)
#pragma unroll
            for (int r = 0; r < 4; r++) {
                int b = lq * 4 + r;
                int t2 = 32 * tis[ii] + 16 * h + lr;
                gpre[ii][h][r] = (b < nb)
                    ? X1t[((size_t)b * DMODEL + d) * LSEQ + t2] : (ushort)0;
            }

    for (int o = 0; o < 2; o++) {
        // ---- build reversed-shifted k copies for this order ----
        const float* krow = kt + ((size_t)o * DMODEL + d) * LSEQ;
        for (int idx = tid; idx < 8 * KCP; idx += 512) {
            int pp = idx / KCP;
            int u = idx - pp * KCP;
            int ki = 1023 - u - pp;
            kc[idx] = f2bf((ki >= 0) ? krow[ki] : 0.f);
        }
        __syncthreads();   // kc ready; prior a_lds writes visible

        f32x4 a00 = {}, a01 = {}, a10 = {}, a11 = {};
        f32x4 a20 = {}, a21 = {}, a30 = {}, a31 = {};
        const char* kbp = (const char*)kc + ((size_t)p * KCP + v0) * 2;
        for (int m = 0; m < 32; m++) {
            bf16x8 b0 = *(const bf16x8*)(kbp - 64 * m);        // h=0
            bf16x8 b1 = *(const bf16x8*)(kbp - 64 * m - 32);   // h=1
            __builtin_amdgcn_s_setprio(1);
#define CSTEP(TI, A0, A1)                                                      \
            if ((TI) >= m) {                                                   \
                bf16x8 af = *(const bf16x8*)((const char*)a_lds +              \
                                             ((a_base + 64 * ((TI) - m)) ^ swz)); \
                A0 = __builtin_amdgcn_mfma_f32_16x16x32_bf16(af, b0, A0, 0, 0, 0); \
                A1 = __builtin_amdgcn_mfma_f32_16x16x32_bf16(af, b1, A1, 0, 0, 0); \
            }
            CSTEP(ti0, a00, a01)
            CSTEP(ti1, a10, a11)
            CSTEP(ti2, a20, a21)
            CSTEP(ti3, a30, a31)
#undef CSTEP
            __builtin_amdgcn_s_setprio(0);
        }
        // ---- epilogue: each (b,t) cell read+written by exactly one lane ----
        float db = Db[o * DMODEL + d];
        __syncthreads();  // all MFMA reads of a_lds and kc complete
#define CEPI(II, TI, AC, H)                                                    \
        {                                                                      \
            _Pragma("unroll")                                                  \
            for (int r = 0; r < 4; r++) {                                      \
                int t2 = 32 * (TI) + 16 * (H) + lr;                            \
                int b = lq * 4 + r;                                            \
                int ab = ((b * 1024 + t2) * 2) ^ (b << 4);                     \
                float a0v = bf2f(*(const ushort*)((const char*)a_lds + ab));   \
                float y = (AC)[r] + a0v * db;                                  \
                if (o == 0) y *= bf2f(gpre[II][H][r]);                         \
                *(ushort*)((char*)a_lds + ab) = f2bf(y);                       \
            }                                                                  \
        }
        CEPI(0, ti0, a00, 0) CEPI(0, ti0, a01, 1)
        CEPI(1, ti1, a10, 0) CEPI(1, ti1, a11, 1)
        CEPI(2, ti2, a20, 0) CEPI(2, ti2, a21, 1)
        CEPI(3, ti3, a30, 0) CEPI(3, ti3, a31, 1)
#undef CEPI
        // next pass's pre-mfma __syncthreads publishes these a_lds writes
    }
    __syncthreads();  // publish o=1 epilogue writes for the writeout
    // ---- writeout ----
    {
        int b = tid >> 5, s = tid & 31;
        if (b < nb) {
            ushort* g = V2t + ((size_t)b * DMODEL + d) * LSEQ + s * 32;
#pragma unroll
            for (int j = 0; j < 4; j++) {   // 4 x 16B = 32 ushorts
                int byte = (b * 1024 + s * 32 + 8 * j) * 2;
                uint4 v = *(const uint4*)((const char*)a_lds + (byte ^ (b << 4)));
                *(uint4*)(g + 8 * j) = v;
            }
        }
    }
}

// ---------------------------------------------------------------------------
// Flat fp32 -> bf16 convert (4 elems/thread)
// ---------------------------------------------------------------------------
__global__ void cvt_bf16(const float* __restrict__ in, ushort* __restrict__ out, int n4) {
    int i = blockIdx.x * blockDim.x + threadIdx.x;
    if (i >= n4) return;
    float4 v = *(const float4*)&in[4 * i];
    uint2 pk;
    pk.x = (uint)f2bf(v.x) | ((uint)f2bf(v.y) << 16);
    pk.y = (uint)f2bf(v.z) | ((uint)f2bf(v.w) << 16);
    *(uint2*)&out[4 * i] = pk;
}

// ---------------------------------------------------------------------------
// Transpose + convert: in [R][C] fp32 -> out [C][R] bf16 (single z)
// ---------------------------------------------------------------------------
__global__ void transpose_cvt(const float* __restrict__ in, ushort* __restrict__ out,
                              int R, int C) {
    __shared__ float tile[32][33];
    int c0 = blockIdx.x * 32, r0 = blockIdx.y * 32;
    int tx = threadIdx.x, ty = threadIdx.y;
#pragma unroll
    for (int i = 0; i < 4; i++)
        tile[ty + 8 * i][tx] = in[(size_t)(r0 + ty + 8 * i) * C + c0 + tx];
    __syncthreads();
#pragma unroll
    for (int i = 0; i < 4; i++)
        out[(size_t)(c0 + ty + 8 * i) * R + r0 + tx] = f2bf(tile[tx][ty + 8 * i]);
}

// ---------------------------------------------------------------------------
// Per-batch bf16 transpose, uint-vectorized: in [b][D][L] -> out [b][L][D]
// ---------------------------------------------------------------------------
__global__ __launch_bounds__(256) void transpose_b16(const ushort* __restrict__ in,
                                                     ushort* __restrict__ out) {
    __shared__ uint tile[64][33];
    int t0 = blockIdx.x * 64, d0 = blockIdx.y * 64, b = blockIdx.z;
    int i = threadIdx.x;
    const ushort* ip = in + (size_t)b * DMODEL * LSEQ;
    ushort* op = out + (size_t)b * LSEQ * DMODEL;
    int dl = i >> 5, cu = i & 31;
#pragma unroll
    for (int j = 0; j < 8; j++)
        tile[dl + 8 * j][cu] =
            *(const uint*)&ip[(size_t)(d0 + dl + 8 * j) * LSEQ + t0 + 2 * cu];
    __syncthreads();
    int du = i & 31, tb = i >> 5;
#pragma unroll
    for (int j = 0; j < 8; j++) {
        int tl = tb + 8 * j;
        uint lo = (tile[2 * du][tl >> 1] >> (16 * (tl & 1))) & 0xFFFFu;
        uint hi = (tile[2 * du + 1][tl >> 1] >> (16 * (tl & 1))) & 0xFFFFu;
        *(uint*)&op[(size_t)(t0 + tl) * DMODEL + d0 + 2 * du] = lo | (hi << 16);
    }
}

// ---------------------------------------------------------------------------
// Parallel bias fuse (r12-proven: replaced a ~70us serial prep stall)
// ---------------------------------------------------------------------------
__global__ void bias_fuse_part(const float* __restrict__ bp,
                               const float* __restrict__ W_in,
                               float* __restrict__ partial) {
    int n = blockIdx.x * 256 + threadIdx.x;
    int k0 = blockIdx.y * 128;
    float s = 0.f;
    for (int k = k0; k < k0 + 128; k++) s += bp[k] * W_in[(size_t)k * D3 + n];
    partial[(size_t)blockIdx.y * D3 + n] = s;
}
__global__ void bias_fuse_red(const float* __restrict__ partial,
                              const float* __restrict__ b_in,
                              float* __restrict__ bf) {
    int n = blockIdx.x * 256 + threadIdx.x;
    float s = b_in[n];
#pragma unroll
    for (int j = 0; j < 8; j++) s += partial[(size_t)j * D3 + n];
    bf[n] = s;
}

// ---------------------------------------------------------------------------
// Transpose k_filt [2][L][D] fp32 -> kt [2][D][L] fp32
// ---------------------------------------------------------------------------
__global__ void transpose_k(const float* __restrict__ kf, float* __restrict__ kt) {
    __shared__ float tile[32][33];
    int s0 = blockIdx.x * 32, d0 = blockIdx.y * 32, o = blockIdx.z;
    int tx = threadIdx.x, ty = threadIdx.y;
#pragma unroll
    for (int i = 0; i < 4; i++)
        tile[ty + 8 * i][tx] = kf[((size_t)o * LSEQ + s0 + ty + 8 * i) * DMODEL + d0 + tx];
    __syncthreads();
#pragma unroll
    for (int i = 0; i < 4; i++)
        kt[((size_t)o * DMODEL + d0 + ty + 8 * i) * LSEQ + s0 + tx] = tile[tx][ty + 8 * i];
}

// ---------------------------------------------------------------------------
// Depthwise causal 3-tap conv on UC [cf,L,3D] bf16 + gating -> bf16 outputs.
// Channel-pair vectorized; all three channel-groups staged at once (1 barrier).
// grid (32, 16, cf), block (32,8)
// ---------------------------------------------------------------------------
__global__ __launch_bounds__(256) void shortconv_gate(const ushort* __restrict__ UC,
                                                      const float* __restrict__ sw,
                                                      const float* __restrict__ sb,
                                                      ushort* __restrict__ At,
                                                      ushort* __restrict__ X1t) {
    __shared__ uint tin[3][34][33];
    __shared__ ushort oA[64][34];
    __shared__ ushort oX[64][34];
    int t0 = blockIdx.x * 32, c0 = blockIdx.y * 64, b = blockIdx.z;
    int tx = threadIdx.x, ty = threadIdx.y;
#pragma unroll
    for (int g = 0; g < 3; g++) {
        int ch = g * DMODEL + c0 + 2 * tx;
        for (int r = ty; r < 34; r += 8) {
            int t = t0 + r - 2;
            tin[g][r][tx] = (t >= 0)
                ? *(const uint*)&UC[((size_t)b * LSEQ + t) * D3 + ch] : 0u;
        }
    }
    __syncthreads();
    float2 res[3][4];
#pragma unroll
    for (int g = 0; g < 3; g++) {
        int ch = g * DMODEL + c0 + 2 * tx;
        float w00 = sw[ch * 3 + 0], w01 = sw[ch * 3 + 1], w02 = sw[ch * 3 + 2];
        float w10 = sw[ch * 3 + 3], w11 = sw[ch * 3 + 4], w12 = sw[ch * 3 + 5];
        float bb0 = sb[ch], bb1 = sb[ch + 1];
#pragma unroll
        for (int i = 0; i < 4; i++) {
            int r = ty + 8 * i + 2;
            uint u0 = tin[g][r - 2][tx], u1 = tin[g][r - 1][tx], u2 = tin[g][r][tx];
            res[g][i].x = w00 * bf2f((ushort)u0) + w01 * bf2f((ushort)u1) +
                          w02 * bf2f((ushort)u2) + bb0;
            res[g][i].y = w10 * bf2f((ushort)(u0 >> 16)) + w11 * bf2f((ushort)(u1 >> 16)) +
                          w12 * bf2f((ushort)(u2 >> 16)) + bb1;
        }
    }
#pragma unroll
    for (int i = 0; i < 4; i++) {
        int t = ty + 8 * i;
        oA[2 * tx][t]     = f2bf(res[2][i].x * res[1][i].x);  // v * x2
        oA[2 * tx + 1][t] = f2bf(res[2][i].y * res[1][i].y);
        oX[2 * tx][t]     = f2bf(res[0][i].x);                // x1
        oX[2 * tx + 1][t] = f2bf(res[0][i].y);
    }
    __syncthreads();
    int li = ty * 32 + tx;              // 0..255
    int row = li >> 2, cu0 = (li & 3) * 4;
    ushort* gA = At  + ((size_t)b * DMODEL + c0 + row) * LSEQ + t0;
    ushort* gX = X1t + ((size_t)b * DMODEL + c0 + row) * LSEQ + t0;
#pragma unroll
    for (int j = 0; j < 4; j++) {
        int cu = cu0 + j;
        uint av = (uint)oA[row][2 * cu] | ((uint)oA[row][2 * cu + 1] << 16);
        uint xv = (uint)oX[row][2 * cu] | ((uint)oX[row][2 * cu + 1] << 16);
        *(uint*)&gA[2 * cu] = av;
        *(uint*)&gX[2 * cu] = xv;
    }
}

// ---------------------------------------------------------------------------
extern "C" void kernel_launch(void* const* d_in, const int* in_sizes, int n_in,
                              void* d_out, int out_size, void* d_ws, size_t ws_size,
                              hipStream_t stream) {
    (void)in_sizes; (void)n_in; (void)out_size;
    const float* x    = (const float*)d_in[0];
    const float* Wp   = (const float*)d_in[1];
    const float* bp   = (const float*)d_in[2];
    const float* W_in = (const float*)d_in[3];
    const float* b_in = (const float*)d_in[4];
    const float* sw   = (const float*)d_in[5];
    const float* sb   = (const float*)d_in[6];
    const float* kf   = (const float*)d_in[7];
    const float* Db   = (const float*)d_in[8];
    const float* Wout = (const float*)d_in[9];
    const float* bout = (const float*)d_in[10];
    float* out = (float*)d_out;

    char* ws = (char*)d_ws;
    // Persistent: Wf_t(3145728) bf(16384) kt(8388608) Wout_t(2097152)
    ushort* Wf_t   = (ushort*)(ws);
    float*  bfv    = (float*)(ws + 3145728);
    float*  kt     = (float*)(ws + 3162112);
    ushort* Wout_t = (ushort*)(ws + 11550720);
    const size_t PB = 13647872;

    // per-batch element sizes (bytes)
    const size_t XB  = 1048576;   // x_bf bf16
    const size_t ATB = 2097152;   // At bf16
    const size_t X1B = 2097152;   // X1t bf16
    const size_t UCB = 6291456;   // UC bf16 (1024*3072*2)
    const size_t V2B = 2097152;   // V2t / V2 bf16
    const size_t PREPB = 7471104; // W_inT + Wp_bf + bias partial scratch floor

    int cb = 1, cf = 1;
    {
        bool ok = false;
        for (int tcb = 16; tcb >= 1 && !ok; tcb >>= 1) {
            for (int tcf = tcb; tcf >= 1; tcf >>= 1) {
                size_t ucreg = (size_t)tcf * UCB;
                size_t v2need = (size_t)2 * tcb * V2B;
                if (ucreg < v2need) ucreg = v2need;
                if (ucreg < PREPB) ucreg = PREPB;
                size_t need = PB + (size_t)tcb * (XB + ATB + X1B) + ucreg;
                if (need <= ws_size) { cb = tcb; cf = tcf; ok = true; break; }
            }
        }
    }

    ushort* x_bf = (ushort*)(ws + PB);
    ushort* Atb  = (ushort*)(ws + PB + (size_t)cb * XB);
    ushort* X1tb = (ushort*)(ws + PB + (size_t)cb * (XB + ATB));
    char*   ucrg = ws + PB + (size_t)cb * (XB + ATB + X1B);
    ushort* UC   = (ushort*)ucrg;
    ushort* V2t  = (ushort*)ucrg;                         // UC dead by conv time
    ushort* V2   = (ushort*)(ucrg + (size_t)cb * V2B);
    // prep scratch aliases the UC region (used before UC is written)
    ushort* W_inT = (ushort*)ucrg;
    ushort* Wp_bf = (ushort*)(ucrg + 6291456);
    float*  bfp   = (float*)(ucrg + 7340032);             // 8x3072 fp32 partials

    // ---- one-time prep ----
    transpose_cvt<<<dim3(96, 32), dim3(32, 8), 0, stream>>>(W_in, W_inT, DMODEL, D3);
    cvt_bf16<<<512, 256, 0, stream>>>(Wp, Wp_bf, DIN * DMODEL / 4);
    // 64x64-tile small GEMM: 384 blocks (vs 48 with the big tile)
    gemm_small<<<dim3(8, 48), 64, 0, stream>>>(W_inT, Wp_bf, Wf_t, D3, DIN, DMODEL);
    bias_fuse_part<<<dim3(12, 8), 256, 0, stream>>>(bp, W_in, bfp);
    bias_fuse_red<<<12, 256, 0, stream>>>(bfp, b_in, bfv);
    transpose_cvt<<<dim3(32, 32), dim3(32, 8), 0, stream>>>(Wout, Wout_t, DMODEL, DMODEL);
    transpose_k<<<dim3(32, 32, 2), dim3(32, 8), 0, stream>>>(kf, kt);

    // ---- super-chunks of cb batches ----
    for (int b0 = 0; b0 < BATCH; b0 += cb) {
        cvt_bf16<<<cb * LSEQ * DIN / 1024, 256, 0, stream>>>(
            x + (size_t)b0 * LSEQ * DIN, x_bf, cb * LSEQ * DIN / 4);
        for (int f0 = 0; f0 < cb; f0 += cf) {
            // UC = x_bf @ Wf + bf   [cf*L, 3072] bf16
            gemm_mfma<ushort, true><<<dim3(24, cf * 4), 512, 0, stream>>>(
                x_bf + (size_t)f0 * LSEQ * DIN, Wf_t, bfv, UC, cf * LSEQ, D3, DIN);
            shortconv_gate<<<dim3(32, 16, cf), dim3(32, 8), 0, stream>>>(
                UC, sw, sb, Atb + (size_t)f0 * DMODEL * LSEQ,
                X1tb + (size_t)f0 * DMODEL * LSEQ);
        }
        // fused long-conv pair (block-Toeplitz MFMA), writes V2t bf16 [b][d][t]
        conv_mfma<<<DMODEL, 512, 0, stream>>>(Atb, X1tb, kt, Db, V2t, cb);
        // V2 [b][t][d] <- V2t [b][d][t]
        transpose_b16<<<dim3(16, 16, cb), dim3(256), 0, stream>>>(V2t, V2);
        // out = V2 @ W_out + b_out
        gemm_mfma<float, true><<<dim3(8, cb * 4), 512, 0, stream>>>(
            V2, Wout_t, bout, out + (size_t)b0 * LSEQ * DMODEL, cb * LSEQ, DMODEL, DMODEL);
    }
}